// Round 5
// baseline (2394.580 us; speedup 1.0000x reference)
//
#include <hip/hip_runtime.h>
#include <cmath>

#define B_ 128
#define T_ 1024
#define D_ 128
#define U_ 256
#define EPS_ 0.01f
#define GAMMA_ 0.01f

typedef float v2f __attribute__((ext_vector_type(2)));

// ================= Kernel 1: h = x @ V + bias =================
// x: [B*T, D] f32, V: [D, U] f32, out: [B*T, U] f32 (h staged into d_out)
#define HG_ROWS 32

__global__ __launch_bounds__(256) void h_gemm_kernel(
    const float* __restrict__ x, const float* __restrict__ V,
    const float* __restrict__ bias, float* __restrict__ out)
{
  const int tid = threadIdx.x;                  // u = tid (0..255)
  const size_t row0 = (size_t)blockIdx.x * HG_ROWS;

  __shared__ float xs[HG_ROWS][D_];             // 16 KB
  __shared__ float vs[32][U_];                  // 32 KB

  {
    const float4* xg = reinterpret_cast<const float4*>(x + row0 * D_);
    float4* xs4 = reinterpret_cast<float4*>(&xs[0][0]);
    #pragma unroll
    for (int i = 0; i < 4; ++i) xs4[i * 256 + tid] = xg[i * 256 + tid];
  }

  float acc[HG_ROWS];
  {
    float b0 = bias[tid];
    #pragma unroll
    for (int r = 0; r < HG_ROWS; ++r) acc[r] = b0;
  }

  for (int c = 0; c < 4; ++c) {
    __syncthreads();
    {
      const float4* vg = reinterpret_cast<const float4*>(V + (size_t)(c * 32) * U_);
      float4* vs4 = reinterpret_cast<float4*>(&vs[0][0]);
      #pragma unroll
      for (int i = 0; i < 8; ++i) vs4[i * 256 + tid] = vg[i * 256 + tid];
    }
    __syncthreads();

    #pragma unroll 2
    for (int d4 = 0; d4 < 8; ++d4) {
      float v0 = vs[d4 * 4 + 0][tid];
      float v1 = vs[d4 * 4 + 1][tid];
      float v2 = vs[d4 * 4 + 2][tid];
      float v3 = vs[d4 * 4 + 3][tid];
      #pragma unroll
      for (int r = 0; r < HG_ROWS; ++r) {
        float4 xr = *reinterpret_cast<const float4*>(&xs[r][c * 32 + d4 * 4]);
        acc[r] = fmaf(xr.x, v0, acc[r]);
        acc[r] = fmaf(xr.y, v1, acc[r]);
        acc[r] = fmaf(xr.z, v2, acc[r]);
        acc[r] = fmaf(xr.w, v3, acc[r]);
      }
    }
  }

  float* og = out + row0 * U_;
  #pragma unroll
  for (int r = 0; r < HG_ROWS; ++r) og[(size_t)r * U_ + tid] = acc[r];
}

// ================= Kernel 2: sequential scan over T =================
// 256 threads/block, one block per batch. Thread u owns output column u and
// the FULL M column in 128 float2 VGPRs (all indices compile-time constant).
// __launch_bounds__(256,1): 1 wave/SIMD -> up to 512 VGPRs, no spill at ~300.
// Double-buffered state in LDS -> ONE barrier per step, no part[] reduction.
// Packed fp32 FMA via llvm.fma.v2f32 -> v_pk_fma_f32 (2x issue rate).
__global__ __launch_bounds__(256, 1) void scan_kernel(
    const float* __restrict__ W, const float* __restrict__ x0,
    float* __restrict__ out)
{
  const int b = blockIdx.x;
  const int u = threadIdx.x;    // 0..255

  // m2[j] = { M[2j][u], M[2j+1][u] },  M[k][u] = W[k][u] - W[u][k] - g*(k==u)
  v2f m2[128];
  {
    const float4* wrow = reinterpret_cast<const float4*>(W + (size_t)u * U_);
    #pragma unroll
    for (int j4 = 0; j4 < 64; ++j4) {
      float4 wu = wrow[j4];                 // W[u][4j4 .. 4j4+3], per-lane contiguous
      const int k = j4 * 4;
      // column reads W[k][u]: coalesced across lanes. gamma folded with
      // compile-time m2[] indices (runtime VALUE select is fine, index is not).
      float c0 = W[(size_t)(k + 0) * U_ + u] - wu.x - ((k + 0) == u ? GAMMA_ : 0.0f);
      float c1 = W[(size_t)(k + 1) * U_ + u] - wu.y - ((k + 1) == u ? GAMMA_ : 0.0f);
      float c2 = W[(size_t)(k + 2) * U_ + u] - wu.z - ((k + 2) == u ? GAMMA_ : 0.0f);
      float c3 = W[(size_t)(k + 3) * U_ + u] - wu.w - ((k + 3) == u ? GAMMA_ : 0.0f);
      m2[j4 * 2 + 0] = v2f{c0, c1};
      m2[j4 * 2 + 1] = v2f{c2, c3};
    }
  }

  __shared__ float state[2][U_];   // 2 KB, double-buffered
  state[0][u] = x0[u];
  float s_reg = x0[u];             // own state kept in a register
  __syncthreads();

  float* outb = out + (size_t)b * T_ * U_;
  // 2-deep h prefetch (h staged in out[], overwritten only at position t)
  float h0 = outb[u];
  float h1 = outb[U_ + u];

  for (int t = 0; t < T_; ++t) {
    // issue h[t+2] load early; latency hidden under this step's FMAs
    float h2 = (t + 2 < T_) ? outb[(size_t)(t + 2) * U_ + u] : 0.0f;

    const float* sp = &state[t & 1][0];
    v2f a0 = {0.0f, 0.0f}, a1 = {0.0f, 0.0f};
    v2f a2 = {0.0f, 0.0f}, a3 = {0.0f, 0.0f};
    #pragma unroll
    for (int j = 0; j < 16; ++j) {   // 16 floats per iter, uniform b128 reads
      float4 sA = *reinterpret_cast<const float4*>(sp + j * 16 + 0);
      float4 sB = *reinterpret_cast<const float4*>(sp + j * 16 + 4);
      float4 sC = *reinterpret_cast<const float4*>(sp + j * 16 + 8);
      float4 sD = *reinterpret_cast<const float4*>(sp + j * 16 + 12);
      a0 = __builtin_elementwise_fma(v2f{sA.x, sA.y}, m2[j * 8 + 0], a0);
      a1 = __builtin_elementwise_fma(v2f{sA.z, sA.w}, m2[j * 8 + 1], a1);
      a2 = __builtin_elementwise_fma(v2f{sB.x, sB.y}, m2[j * 8 + 2], a2);
      a3 = __builtin_elementwise_fma(v2f{sB.z, sB.w}, m2[j * 8 + 3], a3);
      a0 = __builtin_elementwise_fma(v2f{sC.x, sC.y}, m2[j * 8 + 4], a0);
      a1 = __builtin_elementwise_fma(v2f{sC.z, sC.w}, m2[j * 8 + 5], a1);
      a2 = __builtin_elementwise_fma(v2f{sD.x, sD.y}, m2[j * 8 + 6], a2);
      a3 = __builtin_elementwise_fma(v2f{sD.z, sD.w}, m2[j * 8 + 7], a3);
    }
    float dot = ((a0.x + a0.y) + (a1.x + a1.y)) + ((a2.x + a2.y) + (a3.x + a3.y));

    float z = h0 + dot;
    // fast tanh: 1 - 2/(e^{2z}+1); |z| small here, err ~1e-7
    float e = __expf(2.0f * z);
    float th = 1.0f - 2.0f * __builtin_amdgcn_rcpf(e + 1.0f);
    float ns = s_reg + EPS_ * th;
    s_reg = ns;
    state[(t & 1) ^ 1][u] = ns;          // write the OTHER buffer
    outb[(size_t)t * U_ + u] = ns;       // coalesced 1KB store, fire-and-forget
    h0 = h1; h1 = h2;
    __syncthreads();                      // one barrier per step
  }
}

extern "C" void kernel_launch(void* const* d_in, const int* in_sizes, int n_in,
                              void* d_out, int out_size, void* d_ws, size_t ws_size,
                              hipStream_t stream) {
  const float* x    = (const float*)d_in[0];  // [B,T,D]
  const float* V    = (const float*)d_in[1];  // [D,U]
  const float* W    = (const float*)d_in[2];  // [U,U]
  const float* bias = (const float*)d_in[3];  // [U]
  const float* x0   = (const float*)d_in[4];  // [U]
  float* out = (float*)d_out;                 // [B,T,U]

  // Stage h = x@V + bias into d_out, then scan overwrites it in place.
  h_gemm_kernel<<<(B_ * T_) / HG_ROWS, 256, 0, stream>>>(x, V, bias, out);
  scan_kernel<<<B_, 256, 0, stream>>>(W, x0, out);
}

// Round 6
// 1320.204 us; speedup vs baseline: 1.8138x; 1.8138x over previous
//
#include <hip/hip_runtime.h>
#include <cmath>

#define B_ 128
#define T_ 1024
#define D_ 128
#define U_ 256
#define EPS_ 0.01f
#define GAMMA_ 0.01f
#define NB 16            // batches per scan block
#define NBLK (B_ / NB)   // 8 scan blocks

typedef __attribute__((ext_vector_type(8))) short bf16x8;
typedef __attribute__((ext_vector_type(4))) float f32x4;

// f32 -> bf16 round-to-nearest-even (values are tame; no NaN handling needed)
static __device__ __forceinline__ short f2bf(float f) {
  unsigned u = __builtin_bit_cast(unsigned, f);
  unsigned r = (u + 0x7FFFu + ((u >> 16) & 1u)) >> 16;
  return (short)r;
}

// Swizzled byte offset into one bf16 state buffer s[16 rows][256 units].
// Row stride 512 B. XOR bits 4-6 with (row&7): spreads the 16 rows across
// bank windows so the b128 fragment reads hit the LDS BW floor instead of a
// 16-way same-bank serialization. 16-B blocks stay contiguous (bits 0-3 clean).
static __device__ __forceinline__ int sb_byte(int j, int u) {
  return j * 512 + ((u * 2) ^ ((j & 7) << 4));
}

// ================= Kernel 1: h = x @ V + bias (f32, unchanged) =============
#define HG_ROWS 32

__global__ __launch_bounds__(256) void h_gemm_kernel(
    const float* __restrict__ x, const float* __restrict__ V,
    const float* __restrict__ bias, float* __restrict__ out)
{
  const int tid = threadIdx.x;
  const size_t row0 = (size_t)blockIdx.x * HG_ROWS;

  __shared__ float xs[HG_ROWS][D_];
  __shared__ float vs[32][U_];

  {
    const float4* xg = reinterpret_cast<const float4*>(x + row0 * D_);
    float4* xs4 = reinterpret_cast<float4*>(&xs[0][0]);
    #pragma unroll
    for (int i = 0; i < 4; ++i) xs4[i * 256 + tid] = xg[i * 256 + tid];
  }

  float acc[HG_ROWS];
  {
    float b0 = bias[tid];
    #pragma unroll
    for (int r = 0; r < HG_ROWS; ++r) acc[r] = b0;
  }

  for (int c = 0; c < 4; ++c) {
    __syncthreads();
    {
      const float4* vg = reinterpret_cast<const float4*>(V + (size_t)(c * 32) * U_);
      float4* vs4 = reinterpret_cast<float4*>(&vs[0][0]);
      #pragma unroll
      for (int i = 0; i < 8; ++i) vs4[i * 256 + tid] = vg[i * 256 + tid];
    }
    __syncthreads();

    #pragma unroll 2
    for (int d4 = 0; d4 < 8; ++d4) {
      float v0 = vs[d4 * 4 + 0][tid];
      float v1 = vs[d4 * 4 + 1][tid];
      float v2 = vs[d4 * 4 + 2][tid];
      float v3 = vs[d4 * 4 + 3][tid];
      #pragma unroll
      for (int r = 0; r < HG_ROWS; ++r) {
        float4 xr = *reinterpret_cast<const float4*>(&xs[r][c * 32 + d4 * 4]);
        acc[r] = fmaf(xr.x, v0, acc[r]);
        acc[r] = fmaf(xr.y, v1, acc[r]);
        acc[r] = fmaf(xr.z, v2, acc[r]);
        acc[r] = fmaf(xr.w, v3, acc[r]);
      }
    }
  }

  float* og = out + row0 * U_;
  #pragma unroll
  for (int r = 0; r < HG_ROWS; ++r) og[(size_t)r * U_ + tid] = acc[r];
}

// ================= Kernel 2: MFMA scan ======================================
// 8 blocks x 256 threads (4 waves, 1/SIMD). Per step:
//   Z[16][256] = S_bf16 @ M_bf16  via mfma_f32_16x16x32_bf16
// M fragments permanent in VGPRs (128/lane). S double-buffered in LDS.
// Wave w owns u-tiles 4w..4w+3. Lane l: A-row/batch group g=l>>4, col n=l&15.
// Slot map (consistent for A and B, so any hw-internal k permutation cancels):
//   slot (g,e) of k-tile kt -> k = kt*32 + 8*g + e
// C/D layout (m89-verified): col = l&15, row = 4*(l>>4) + reg.
__global__ __launch_bounds__(256, 1) void scan_mfma_kernel(
    const float* __restrict__ W, const float* __restrict__ x0,
    float* __restrict__ out)
{
  __shared__ __align__(16) char sbuf[2][16 * 512];  // bf16 S, dbuf, swizzled

  const int tid = threadIdx.x;
  const int w = tid >> 6;     // wave 0..3
  const int l = tid & 63;
  const int g = l >> 4;       // 0..3
  const int n16 = l & 15;
  const int b0 = blockIdx.x * NB;

  // ---- B fragments (static M columns), built once from W by explicit formula
  bf16x8 bfrag[4][8];
  #pragma unroll
  for (int c = 0; c < 4; ++c) {
    const int u = 64 * w + 16 * c + n16;
    #pragma unroll
    for (int kt = 0; kt < 8; ++kt) {
      #pragma unroll
      for (int e = 0; e < 8; ++e) {
        const int k = kt * 32 + 8 * g + e;
        float mv = W[(size_t)k * U_ + u] - W[(size_t)u * U_ + k]
                   - ((k == u) ? GAMMA_ : 0.0f);
        bfrag[c][kt][e] = f2bf(mv);
      }
    }
  }

  // ---- f32 master state (lane owns rows j=4g+i, cols u(c)); init = x0[u]
  float s_f32[4][4];
  #pragma unroll
  for (int c = 0; c < 4; ++c) {
    float v = x0[64 * w + 16 * c + n16];
    #pragma unroll
    for (int i = 0; i < 4; ++i) s_f32[c][i] = v;
  }

  // ---- init bf16 state buffer 0 (cooperative: thread tid handles unit u=tid)
  {
    short v = f2bf(x0[tid]);
    #pragma unroll
    for (int j = 0; j < 16; ++j)
      *(short*)(&sbuf[0][sb_byte(j, tid)]) = v;
  }
  __syncthreads();

  // ---- h prefetch for t=0 (h staged in out[] by h_gemm_kernel)
  float h_nxt[4][4];
  #pragma unroll
  for (int c = 0; c < 4; ++c) {
    const int u = 64 * w + 16 * c + n16;
    #pragma unroll
    for (int i = 0; i < 4; ++i)
      h_nxt[c][i] = out[(size_t)(b0 + 4 * g + i) * (T_ * U_) + u];
  }

  for (int t = 0; t < T_; ++t) {
    float h_cur[4][4];
    #pragma unroll
    for (int c = 0; c < 4; ++c)
      #pragma unroll
      for (int i = 0; i < 4; ++i) h_cur[c][i] = h_nxt[c][i];

    // issue next step's h loads early (hidden under MFMA phase)
    if (t + 1 < T_) {
      #pragma unroll
      for (int c = 0; c < 4; ++c) {
        const int u = 64 * w + 16 * c + n16;
        #pragma unroll
        for (int i = 0; i < 4; ++i)
          h_nxt[c][i] = out[(size_t)(b0 + 4 * g + i) * (T_ * U_)
                            + (size_t)(t + 1) * U_ + u];
      }
    }

    // ---- A fragments: row j=n16, slots (g,e) -> units kt*32+8g+e, one b128 each
    const char* sb = sbuf[t & 1];
    bf16x8 af[8];
    #pragma unroll
    for (int kt = 0; kt < 8; ++kt)
      af[kt] = *(const bf16x8*)(sb + n16 * 512
                                + ((kt * 64 + 16 * g) ^ ((n16 & 7) << 4)));

    // ---- MFMA: 4 col-tiles x 8 k-tiles, acc chained over k
    f32x4 acc[4];
    #pragma unroll
    for (int c = 0; c < 4; ++c) {
      acc[c] = (f32x4){0.f, 0.f, 0.f, 0.f};
      #pragma unroll
      for (int kt = 0; kt < 8; ++kt)
        acc[c] = __builtin_amdgcn_mfma_f32_16x16x32_bf16(
            af[kt], bfrag[c][kt], acc[c], 0, 0, 0);
    }

    // ---- epilogue: z = d + h; tanh; state update; write bf16 S + f32 out
    char* sw = sbuf[(t & 1) ^ 1];
    #pragma unroll
    for (int c = 0; c < 4; ++c) {
      const int u = 64 * w + 16 * c + n16;
      #pragma unroll
      for (int i = 0; i < 4; ++i) {
        float z = acc[c][i] + h_cur[c][i];
        float e2 = __expf(2.0f * z);
        float th = 1.0f - 2.0f * __builtin_amdgcn_rcpf(e2 + 1.0f);
        float ns = s_f32[c][i] + EPS_ * th;
        s_f32[c][i] = ns;
        *(short*)(sw + sb_byte(4 * g + i, u)) = f2bf(ns);
        out[(size_t)(b0 + 4 * g + i) * (T_ * U_) + (size_t)t * U_ + u] = ns;
      }
    }
    __syncthreads();
  }
}

extern "C" void kernel_launch(void* const* d_in, const int* in_sizes, int n_in,
                              void* d_out, int out_size, void* d_ws, size_t ws_size,
                              hipStream_t stream) {
  const float* x    = (const float*)d_in[0];  // [B,T,D]
  const float* V    = (const float*)d_in[1];  // [D,U]
  const float* W    = (const float*)d_in[2];  // [U,U]
  const float* bias = (const float*)d_in[3];  // [U]
  const float* x0   = (const float*)d_in[4];  // [U]
  float* out = (float*)d_out;                 // [B,T,U]

  // Stage h = x@V + bias into d_out, then scan overwrites it in place.
  h_gemm_kernel<<<(B_ * T_) / HG_ROWS, 256, 0, stream>>>(x, V, bias, out);
  scan_mfma_kernel<<<NBLK, 256, 0, stream>>>(W, x0, out);
}